// Round 3
// baseline (2423.349 us; speedup 1.0000x reference)
//
#include <hip/hip_runtime.h>
#include <hip/hip_bf16.h>
#include <stdint.h>

// Per-token-independent chain => tile over M with chunk size adapted to
// ws_size. Fixed ws: Wlb 8MB | Wc1b 32MB | Wc2b 8MB | Wsb 2MB | xb 64MB
// (= 114MB), then two bf16 chunk buffers [Mc,4096].

typedef short bf16x8 __attribute__((ext_vector_type(8)));
typedef float f32x4 __attribute__((ext_vector_type(4)));

#define GLOAD_LDS16(g, l)                                                     \
  __builtin_amdgcn_global_load_lds(                                           \
      (const __attribute__((address_space(1))) void*)(g),                     \
      (__attribute__((address_space(3))) void*)(l), 16, 0, 0)

__device__ __forceinline__ ushort f2b(float f) {
  uint32_t u = __builtin_bit_cast(uint32_t, f);
  u += 0x7fffu + ((u >> 16) & 1u);
  return (ushort)(u >> 16);
}

// ---------------- prep: fp32 -> bf16 with optional per-128x128-block scale --
__global__ __launch_bounds__(256) void cvt_scale(
    const float* __restrict__ src, ushort* __restrict__ dst, long n4, int cols,
    const float* __restrict__ scale, int scols) {
  long i = (long)blockIdx.x * blockDim.x + threadIdx.x;
  long stride = (long)gridDim.x * blockDim.x;
  for (; i < n4; i += stride) {
    long e = i * 4;
    float4 v = ((const float4*)src)[i];
    float s = 1.f;
    if (scale) {
      int r = (int)(e / cols), c = (int)(e % cols);
      s = scale[(r >> 7) * scols + (c >> 7)];
    }
    ushort4 o;
    o.x = f2b(v.x * s); o.y = f2b(v.y * s);
    o.z = f2b(v.z * s); o.w = f2b(v.w * s);
    ((ushort4*)dst)[i] = o;
  }
}

// Wsum = dequant(W_s1,s_s1) + dequant(W_s2,s_s2), [1024,1024] -> bf16
__global__ __launch_bounds__(256) void make_wsum(
    const float* __restrict__ W1, const float* __restrict__ s1,
    const float* __restrict__ W2, const float* __restrict__ s2,
    ushort* __restrict__ dst) {
  const long n4 = (1024L * 1024L) / 4;
  long i = (long)blockIdx.x * blockDim.x + threadIdx.x;
  long stride = (long)gridDim.x * blockDim.x;
  for (; i < n4; i += stride) {
    long e = i * 4;
    int r = (int)(e >> 10), c = (int)(e & 1023);
    int si = (r >> 7) * 8 + (c >> 7);
    float f1 = s1[si], f2 = s2[si];
    float4 a = ((const float4*)W1)[i];
    float4 b = ((const float4*)W2)[i];
    ushort4 o;
    o.x = f2b(a.x * f1 + b.x * f2); o.y = f2b(a.y * f1 + b.y * f2);
    o.z = f2b(a.z * f1 + b.z * f2); o.w = f2b(a.w * f1 + b.w * f2);
    ((ushort4*)dst)[i] = o;
  }
}

// ---------------- GEMM: C[m,n] = sum_k A[m,k]*B[n,k]  (B^T layout) ----------
// 128x128 tile, BK=32, 4 waves (2x2), 16x16x32 bf16 MFMA, m97 structure.
// Dual K-segment: K1 over (A1,B1) then K2 over (A2,B2) into the same acc.
// EPI 0: relu -> bf16 store.  EPI 1: plain f32 store.
template <int EPI>
__global__ __launch_bounds__(256, 2) void gemm_bt(
    const ushort* __restrict__ A1, const ushort* __restrict__ B1, int lda1,
    int ldb1, int K1, const ushort* __restrict__ A2,
    const ushort* __restrict__ B2, int lda2, int ldb2, int K2,
    void* __restrict__ Cout, int N) {
  __shared__ __align__(16) ushort As[128 * 32];
  __shared__ __align__(16) ushort Bs[128 * 32];
  const int t = threadIdx.x;
  const int l = t & 63;
  const int w = t >> 6;
  const int wr = w >> 1, wc = w & 1;   // 2x2 wave grid, each wave 64x64 out
  const int fr = l & 15, fq = l >> 4;  // fragment row / k-group

  const int n0 = blockIdx.x * 128;
  const int m0 = blockIdx.y * 128;

  f32x4 acc[4][4];
#pragma unroll
  for (int i = 0; i < 4; i++)
#pragma unroll
    for (int j = 0; j < 4; j++) acc[i][j] = (f32x4){0.f, 0.f, 0.f, 0.f};

  // staging map: lane l of wave w covers LDS bytes [w*1024 + l*16) per chunk
  const int srow = t >> 2;            // row within 64-row chunk
  const int scol = (t & 3) * 8;       // k offset (elements)
  const int wbase = (t >> 6) * 1024;  // wave-uniform LDS byte base in chunk

  const int KT = (K1 + K2) >> 5;
  for (int kt = 0; kt < KT; ++kt) {
    const ushort* Ap;
    const ushort* Bp;
    int lda, ldb, k0;
    const int kk = kt << 5;
    if (kk < K1) {
      Ap = A1; Bp = B1; lda = lda1; ldb = ldb1; k0 = kk;
    } else {
      Ap = A2; Bp = B2; lda = lda2; ldb = ldb2; k0 = kk - K1;
    }

    __syncthreads();  // previous tile's reads done before overwrite
#pragma unroll
    for (int c = 0; c < 2; ++c) {
      const ushort* ga = Ap + (size_t)(m0 + c * 64 + srow) * lda + (k0 + scol);
      GLOAD_LDS16(ga, (char*)As + c * 4096 + wbase);
      const ushort* gb = Bp + (size_t)(n0 + c * 64 + srow) * ldb + (k0 + scol);
      GLOAD_LDS16(gb, (char*)Bs + c * 4096 + wbase);
    }
    __syncthreads();  // compiler drains vmcnt(0) before barrier

    bf16x8 af[4], bfr[4];
#pragma unroll
    for (int mi = 0; mi < 4; mi++)
      af[mi] = *(const bf16x8*)&As[(wr * 64 + mi * 16 + fr) * 32 + fq * 8];
#pragma unroll
    for (int ni = 0; ni < 4; ni++)
      bfr[ni] = *(const bf16x8*)&Bs[(wc * 64 + ni * 16 + fr) * 32 + fq * 8];
#pragma unroll
    for (int mi = 0; mi < 4; mi++)
#pragma unroll
      for (int ni = 0; ni < 4; ni++)
        acc[mi][ni] = __builtin_amdgcn_mfma_f32_16x16x32_bf16(
            af[mi], bfr[ni], acc[mi][ni], 0, 0, 0);
  }

  // epilogue: C/D layout col=lane&15, row=(lane>>4)*4+reg (m89-verified)
#pragma unroll
  for (int mi = 0; mi < 4; mi++) {
#pragma unroll
    for (int ni = 0; ni < 4; ni++) {
#pragma unroll
      for (int j = 0; j < 4; j++) {
        const int row = m0 + wr * 64 + mi * 16 + fq * 4 + j;
        const int col = n0 + wc * 64 + ni * 16 + fr;
        const float v = acc[mi][ni][j];
        if (EPI == 0) {
          ((ushort*)Cout)[(size_t)row * N + col] = f2b(fmaxf(v, 0.f));
        } else {
          ((float*)Cout)[(size_t)row * N + col] = v;
        }
      }
    }
  }
}

// ---------------- LayerNorm in-place over rows of 1024 f32 -----------------
__global__ __launch_bounds__(256) void ln_inplace(
    float* __restrict__ buf, const float* __restrict__ gamma,
    const float* __restrict__ beta) {
  const int t = threadIdx.x;
  float* row = buf + (size_t)blockIdx.x * 1024;
  float4 v = ((const float4*)row)[t];
  float s = v.x + v.y + v.z + v.w;
  float ss = v.x * v.x + v.y * v.y + v.z * v.z + v.w * v.w;
#pragma unroll
  for (int off = 32; off > 0; off >>= 1) {
    s += __shfl_down(s, off, 64);
    ss += __shfl_down(ss, off, 64);
  }
  __shared__ float red_s[4], red_ss[4];
  if ((t & 63) == 0) {
    red_s[t >> 6] = s;
    red_ss[t >> 6] = ss;
  }
  __syncthreads();
  const float tot = red_s[0] + red_s[1] + red_s[2] + red_s[3];
  const float tot2 = red_ss[0] + red_ss[1] + red_ss[2] + red_ss[3];
  const float mu = tot * (1.f / 1024.f);
  const float var = tot2 * (1.f / 1024.f) - mu * mu;
  const float rs = rsqrtf(var + 1e-5f);
  const float4 g = ((const float4*)gamma)[t];
  const float4 b = ((const float4*)beta)[t];
  float4 o;
  o.x = (v.x - mu) * rs * g.x + b.x;
  o.y = (v.y - mu) * rs * g.y + b.y;
  o.z = (v.z - mu) * rs * g.z + b.z;
  o.w = (v.w - mu) * rs * g.w + b.w;
  ((float4*)row)[t] = o;
}

extern "C" void kernel_launch(void* const* d_in, const int* in_sizes, int n_in,
                              void* d_out, int out_size, void* d_ws,
                              size_t ws_size, hipStream_t stream) {
  const float* x = (const float*)d_in[0];
  const float* W_large = (const float*)d_in[1];
  const float* W_s1 = (const float*)d_in[2];
  const float* W_s2 = (const float*)d_in[3];
  const float* W_c1 = (const float*)d_in[4];
  const float* W_c2 = (const float*)d_in[5];
  const float* gamma = (const float*)d_in[6];
  const float* beta = (const float*)d_in[7];
  const float* s_large = (const float*)d_in[8];
  const float* s_s1 = (const float*)d_in[9];
  const float* s_s2 = (const float*)d_in[10];

  const long BT = 32768;  // 8*4096 tokens

  char* ws = (char*)d_ws;
  size_t off = 0;
  ushort* Wlb  = (ushort*)(ws + off); off += 4096L * 1024 * 2;   //  8MB
  ushort* Wc1b = (ushort*)(ws + off); off += 4096L * 4096 * 2;   // 32MB
  ushort* Wc2b = (ushort*)(ws + off); off += 1024L * 4096 * 2;   //  8MB
  ushort* Wsb  = (ushort*)(ws + off); off += 1024L * 1024 * 2;   //  2MB
  ushort* xb   = (ushort*)(ws + off); off += BT * 1024 * 2;      // 64MB

  // chunk size over M: largest multiple of 128 fitting two [Mc,4096] bf16 bufs
  size_t remain = (ws_size > off) ? (ws_size - off) : 0;
  long Mc = (long)(remain / 2 / (4096 * 2));
  Mc = (Mc / 128) * 128;
  if (Mc > BT) Mc = BT;
  if (Mc < 128) Mc = 128;  // below this nothing fits anyway
  ushort* big1 = (ushort*)(ws + off);
  ushort* big2 = big1 + (size_t)Mc * 4096;

  // prep: bf16 conversions (scales folded into weights)
  cvt_scale<<<2048, 256, 0, stream>>>(x, xb, BT * 1024 / 4, 1024, nullptr, 0);
  cvt_scale<<<1024, 256, 0, stream>>>(W_large, Wlb, 4194304L / 4, 1024,
                                      s_large, 8);
  cvt_scale<<<2048, 256, 0, stream>>>(W_c1, Wc1b, 16777216L / 4, 4096, nullptr,
                                      0);
  cvt_scale<<<1024, 256, 0, stream>>>(W_c2, Wc2b, 4194304L / 4, 4096, nullptr,
                                      0);
  make_wsum<<<512, 256, 0, stream>>>(W_s1, s_s1, W_s2, s_s2, Wsb);

  for (long m = 0; m < BT; m += Mc) {
    const long mc = (BT - m < Mc) ? (BT - m) : Mc;
    const int mb = (int)(mc / 128);
    const ushort* xc = xb + m * 1024;
    // big1 = relu(xc @ Wl^T)   [mc,4096]
    gemm_bt<0><<<dim3(32, mb), 256, 0, stream>>>(
        xc, Wlb, 1024, 1024, 1024, xc, Wlb, 1024, 1024, 0, big1, 4096);
    // big2 = relu(big1 @ Wc1^T)  [mc,4096]
    gemm_bt<0><<<dim3(32, mb), 256, 0, stream>>>(
        big1, Wc1b, 4096, 4096, 4096, big1, Wc1b, 4096, 4096, 0, big2, 4096);
    // out_chunk = big2 @ Wc2^T + xc @ Wsum^T  [mc,1024]  (fused dual-K)
    gemm_bt<1><<<dim3(8, mb), 256, 0, stream>>>(
        big2, Wc2b, 4096, 4096, 4096, xc, Wsb, 1024, 1024, 1024,
        (float*)d_out + m * 1024, 1024);
  }
  // LayerNorm in place over the full output
  ln_inplace<<<(int)BT, 256, 0, stream>>>((float*)d_out, gamma, beta);
}

// Round 4
// 2279.198 us; speedup vs baseline: 1.0632x; 1.0632x over previous
//
#include <hip/hip_runtime.h>
#include <hip/hip_bf16.h>
#include <stdint.h>

// R4: 256^2-tile 8-wave deep-pipelined GEMM (T1+T3+T4+T5), BK=32,
// 4-deep circular LDS (128KB), counted vmcnt(8) per K-tile (never 0 in
// steady state), raw s_barrier, setprio around MFMA clusters.
// ws: Wlb 8MB | Wc1b 32MB | Wc2b 8MB | Wsb 2MB | xb 64MB | big1/big2 chunks.

typedef short bf16x8 __attribute__((ext_vector_type(8)));
typedef float f32x4 __attribute__((ext_vector_type(4)));

#define GLOAD_LDS16(g, l)                                                     \
  __builtin_amdgcn_global_load_lds(                                           \
      (const __attribute__((address_space(1))) void*)(g),                     \
      (__attribute__((address_space(3))) void*)(l), 16, 0, 0)

__device__ __forceinline__ ushort f2b(float f) {
  uint32_t u = __builtin_bit_cast(uint32_t, f);
  u += 0x7fffu + ((u >> 16) & 1u);
  return (ushort)(u >> 16);
}

// ---------------- prep: fp32 -> bf16 with optional per-128x128-block scale --
__global__ __launch_bounds__(256) void cvt_scale(
    const float* __restrict__ src, ushort* __restrict__ dst, long n4, int cols,
    const float* __restrict__ scale, int scols) {
  long i = (long)blockIdx.x * blockDim.x + threadIdx.x;
  long stride = (long)gridDim.x * blockDim.x;
  for (; i < n4; i += stride) {
    long e = i * 4;
    float4 v = ((const float4*)src)[i];
    float s = 1.f;
    if (scale) {
      int r = (int)(e / cols), c = (int)(e % cols);
      s = scale[(r >> 7) * scols + (c >> 7)];
    }
    ushort4 o;
    o.x = f2b(v.x * s); o.y = f2b(v.y * s);
    o.z = f2b(v.z * s); o.w = f2b(v.w * s);
    ((ushort4*)dst)[i] = o;
  }
}

__global__ __launch_bounds__(256) void make_wsum(
    const float* __restrict__ W1, const float* __restrict__ s1,
    const float* __restrict__ W2, const float* __restrict__ s2,
    ushort* __restrict__ dst) {
  const long n4 = (1024L * 1024L) / 4;
  long i = (long)blockIdx.x * blockDim.x + threadIdx.x;
  long stride = (long)gridDim.x * blockDim.x;
  for (; i < n4; i += stride) {
    long e = i * 4;
    int r = (int)(e >> 10), c = (int)(e & 1023);
    int si = (r >> 7) * 8 + (c >> 7);
    float f1 = s1[si], f2 = s2[si];
    float4 a = ((const float4*)W1)[i];
    float4 b = ((const float4*)W2)[i];
    ushort4 o;
    o.x = f2b(a.x * f1 + b.x * f2); o.y = f2b(a.y * f1 + b.y * f2);
    o.z = f2b(a.z * f1 + b.z * f2); o.w = f2b(a.w * f1 + b.w * f2);
    ((ushort4*)dst)[i] = o;
  }
}

// ---------------- deep-pipelined GEMM: C[m,n] = sum_k A[m,k]*B[n,k] ---------
// 256x256 tile, BK=32, 512 thr (8 waves, 2Mx4N), per-wave 128x64 out.
// LDS: 4 circular bufs x (A 16KB + B 16KB) = 128KB. Stage tile t+3 during
// tile t. vmcnt(8) at K-tile boundary. Dual-K segment support.
// EPI 0: relu -> bf16.  EPI 1: f32.
template <int EPI>
__global__ __launch_bounds__(512, 2) void gemm8(
    const ushort* __restrict__ A1, const ushort* __restrict__ B1, int lda1,
    int ldb1, int K1, const ushort* __restrict__ A2,
    const ushort* __restrict__ B2, int lda2, int ldb2, int K2,
    void* __restrict__ Cout, int N, int gridN) {
  extern __shared__ __align__(16) char lds[];  // 131072 bytes

  const int t = threadIdx.x;
  const int l = t & 63;
  const int wid = t >> 6;              // 0..7
  const int wr = wid >> 2;             // 0..1  (M half)
  const int wc = wid & 3;              // 0..3  (N quarter)
  const int fr = l & 15, fq = l >> 4;  // fragment row / 16B col group

  // XCD-aware bijective block swizzle (m204)
  const int nwg = gridDim.x;
  {
  }
  int bid = blockIdx.x;
  const int xcd = bid & 7, idx = bid >> 3;
  const int q = nwg >> 3, r = nwg & 7;
  const int swz = ((xcd < r) ? xcd * (q + 1) : r * (q + 1) + (xcd - r) * q) +
                  idx;
  const int m0 = (swz / gridN) * 256;
  const int n0 = (swz % gridN) * 256;

  // staging map: unit = 8KB = 128 rows x 64B; thread t covers bytes t*16
  const int srow = wid * 16 + (l >> 2);  // row within 128-row unit
  const int scol = (l & 3) * 8;          // k offset (elements)

  // fragment read byte offsets within a buffer (rows are 64B)
  const int aoff = (wr * 128 + fr) * 64 + fq * 16;
  const int boff = (wc * 64 + fr) * 64 + fq * 16;

  const int NT = (K1 + K2) >> 5;

  auto stageA = [&](int tt, int sb) {
    int kk = tt << 5;
    const ushort* P;
    int ld;
    if (kk < K1) {
      P = A1; ld = lda1;
    } else {
      P = A2; ld = lda2; kk -= K1;
    }
    const ushort* s0 = P + (size_t)(m0 + srow) * ld + kk + scol;
    char* d0 = lds + sb * 32768 + wid * 1024;
    GLOAD_LDS16(s0, d0);
    GLOAD_LDS16(s0 + (size_t)128 * ld, d0 + 8192);
  };
  auto stageB = [&](int tt, int sb) {
    int kk = tt << 5;
    const ushort* P;
    int ld;
    if (kk < K1) {
      P = B1; ld = ldb1;
    } else {
      P = B2; ld = ldb2; kk -= K1;
    }
    const ushort* s0 = P + (size_t)(n0 + srow) * ld + kk + scol;
    char* d0 = lds + sb * 32768 + 16384 + wid * 1024;
    GLOAD_LDS16(s0, d0);
    GLOAD_LDS16(s0 + (size_t)128 * ld, d0 + 8192);
  };

  f32x4 acc[8][4];
#pragma unroll
  for (int i = 0; i < 8; i++)
#pragma unroll
    for (int j = 0; j < 4; j++) acc[i][j] = (f32x4){0.f, 0.f, 0.f, 0.f};

  // prologue: stage tiles 0,1,2 (12 loads/wave); wait until tile0 landed.
  stageA(0, 0); stageB(0, 0);
  stageA(1, 1); stageB(1, 1);
  stageA(2, 2); stageB(2, 2);
  asm volatile("s_waitcnt vmcnt(8)" ::: "memory");
  __builtin_amdgcn_s_barrier();

  for (int kt = 0; kt < NT; ++kt) {
    const int b = kt & 3;
    const char* Ab = lds + b * 32768;
    const char* Bb = Ab + 16384;
    const bool sOK = (kt + 3 < NT);
    const int sb = (kt + 3) & 3;

    // ---------------- phase A: mi 0..3 ----------------
    bf16x8 bfr[4], af[4];
#pragma unroll
    for (int ni = 0; ni < 4; ++ni)
      bfr[ni] = *(const bf16x8*)(Bb + boff + ni * 1024);
#pragma unroll
    for (int mi = 0; mi < 4; ++mi)
      af[mi] = *(const bf16x8*)(Ab + aoff + mi * 1024);
    if (sOK) stageA(kt + 3, sb);
    __builtin_amdgcn_s_barrier();
    asm volatile("s_waitcnt lgkmcnt(0)" ::: "memory");
    __builtin_amdgcn_sched_barrier(0);
    __builtin_amdgcn_s_setprio(1);
#pragma unroll
    for (int mi = 0; mi < 4; ++mi)
#pragma unroll
      for (int ni = 0; ni < 4; ++ni)
        acc[mi][ni] = __builtin_amdgcn_mfma_f32_16x16x32_bf16(
            af[mi], bfr[ni], acc[mi][ni], 0, 0, 0);
    __builtin_amdgcn_s_setprio(0);
    __builtin_amdgcn_s_barrier();

    // ---------------- phase B: mi 4..7 ----------------
#pragma unroll
    for (int mi = 0; mi < 4; ++mi)
      af[mi] = *(const bf16x8*)(Ab + aoff + (mi + 4) * 1024);
    if (sOK) stageB(kt + 3, sb);
    __builtin_amdgcn_s_barrier();
    asm volatile("s_waitcnt lgkmcnt(0)" ::: "memory");
    __builtin_amdgcn_sched_barrier(0);
    __builtin_amdgcn_s_setprio(1);
#pragma unroll
    for (int mi = 0; mi < 4; ++mi)
#pragma unroll
      for (int ni = 0; ni < 4; ++ni)
        acc[mi + 4][ni] = __builtin_amdgcn_mfma_f32_16x16x32_bf16(
            af[mi], bfr[ni], acc[mi + 4][ni], 0, 0, 0);
    __builtin_amdgcn_s_setprio(0);
    // K-tile boundary: keep tiles {kt+2, kt+3} in flight (8 loads); drain tail
    if (kt + 4 <= NT) {
      asm volatile("s_waitcnt vmcnt(8)" ::: "memory");
    } else if (kt + 3 == NT) {
      asm volatile("s_waitcnt vmcnt(4)" ::: "memory");
    } else if (kt + 2 == NT) {
      asm volatile("s_waitcnt vmcnt(0)" ::: "memory");
    }
    __builtin_amdgcn_s_barrier();
  }

  // epilogue: C/D 16x16 layout col=lane&15, row=(lane>>4)*4+reg
#pragma unroll
  for (int mi = 0; mi < 8; ++mi) {
#pragma unroll
    for (int ni = 0; ni < 4; ++ni) {
#pragma unroll
      for (int j = 0; j < 4; ++j) {
        const int row = m0 + wr * 128 + mi * 16 + fq * 4 + j;
        const int col = n0 + wc * 64 + ni * 16 + fr;
        const float v = acc[mi][ni][j];
        if (EPI == 0) {
          ((ushort*)Cout)[(size_t)row * N + col] = f2b(fmaxf(v, 0.f));
        } else {
          ((float*)Cout)[(size_t)row * N + col] = v;
        }
      }
    }
  }
}

// ---------------- LayerNorm in-place over rows of 1024 f32 -----------------
__global__ __launch_bounds__(256) void ln_inplace(
    float* __restrict__ buf, const float* __restrict__ gamma,
    const float* __restrict__ beta) {
  const int t = threadIdx.x;
  float* row = buf + (size_t)blockIdx.x * 1024;
  float4 v = ((const float4*)row)[t];
  float s = v.x + v.y + v.z + v.w;
  float ss = v.x * v.x + v.y * v.y + v.z * v.z + v.w * v.w;
#pragma unroll
  for (int off = 32; off > 0; off >>= 1) {
    s += __shfl_down(s, off, 64);
    ss += __shfl_down(ss, off, 64);
  }
  __shared__ float red_s[4], red_ss[4];
  if ((t & 63) == 0) {
    red_s[t >> 6] = s;
    red_ss[t >> 6] = ss;
  }
  __syncthreads();
  const float tot = red_s[0] + red_s[1] + red_s[2] + red_s[3];
  const float tot2 = red_ss[0] + red_ss[1] + red_ss[2] + red_ss[3];
  const float mu = tot * (1.f / 1024.f);
  const float var = tot2 * (1.f / 1024.f) - mu * mu;
  const float rs = rsqrtf(var + 1e-5f);
  const float4 g = ((const float4*)gamma)[t];
  const float4 b = ((const float4*)beta)[t];
  float4 o;
  o.x = (v.x - mu) * rs * g.x + b.x;
  o.y = (v.y - mu) * rs * g.y + b.y;
  o.z = (v.z - mu) * rs * g.z + b.z;
  o.w = (v.w - mu) * rs * g.w + b.w;
  ((float4*)row)[t] = o;
}

extern "C" void kernel_launch(void* const* d_in, const int* in_sizes, int n_in,
                              void* d_out, int out_size, void* d_ws,
                              size_t ws_size, hipStream_t stream) {
  const float* x = (const float*)d_in[0];
  const float* W_large = (const float*)d_in[1];
  const float* W_s1 = (const float*)d_in[2];
  const float* W_s2 = (const float*)d_in[3];
  const float* W_c1 = (const float*)d_in[4];
  const float* W_c2 = (const float*)d_in[5];
  const float* gamma = (const float*)d_in[6];
  const float* beta = (const float*)d_in[7];
  const float* s_large = (const float*)d_in[8];
  const float* s_s1 = (const float*)d_in[9];
  const float* s_s2 = (const float*)d_in[10];

  const long BT = 32768;  // 8*4096 tokens

  char* ws = (char*)d_ws;
  size_t off = 0;
  ushort* Wlb  = (ushort*)(ws + off); off += 4096L * 1024 * 2;   //  8MB
  ushort* Wc1b = (ushort*)(ws + off); off += 4096L * 4096 * 2;   // 32MB
  ushort* Wc2b = (ushort*)(ws + off); off += 1024L * 4096 * 2;   //  8MB
  ushort* Wsb  = (ushort*)(ws + off); off += 1024L * 1024 * 2;   //  2MB
  ushort* xb   = (ushort*)(ws + off); off += BT * 1024 * 2;      // 64MB

  // chunk over M: largest multiple of 256 fitting two [Mc,4096] bf16 bufs
  size_t remain = (ws_size > off) ? (ws_size - off) : 0;
  long Mc = (long)(remain / 2 / (4096 * 2));
  Mc = (Mc / 256) * 256;
  if (Mc > BT) Mc = BT;
  if (Mc < 256) Mc = 256;
  ushort* big1 = (ushort*)(ws + off);
  ushort* big2 = big1 + (size_t)Mc * 4096;

  // prep: bf16 conversions (scales folded into weights)
  cvt_scale<<<2048, 256, 0, stream>>>(x, xb, BT * 1024 / 4, 1024, nullptr, 0);
  cvt_scale<<<1024, 256, 0, stream>>>(W_large, Wlb, 4194304L / 4, 1024,
                                      s_large, 8);
  cvt_scale<<<2048, 256, 0, stream>>>(W_c1, Wc1b, 16777216L / 4, 4096, nullptr,
                                      0);
  cvt_scale<<<1024, 256, 0, stream>>>(W_c2, Wc2b, 4194304L / 4, 4096, nullptr,
                                      0);
  make_wsum<<<512, 256, 0, stream>>>(W_s1, s_s1, W_s2, s_s2, Wsb);

  const int LDS = 131072;
  for (long m = 0; m < BT; m += Mc) {
    const long mc = (BT - m < Mc) ? (BT - m) : Mc;
    const int mb = (int)(mc / 256);
    const ushort* xc = xb + m * 1024;
    // big1 = relu(xc @ Wl^T)   [mc,4096]
    gemm8<0><<<mb * 16, 512, LDS, stream>>>(
        xc, Wlb, 1024, 1024, 1024, xc, Wlb, 1024, 1024, 0, big1, 4096, 16);
    // big2 = relu(big1 @ Wc1^T)  [mc,4096]
    gemm8<0><<<mb * 16, 512, LDS, stream>>>(
        big1, Wc1b, 4096, 4096, 4096, big1, Wc1b, 4096, 4096, 0, big2, 4096,
        16);
    // out_chunk = big2 @ Wc2^T + xc @ Wsum^T  [mc,1024]  (fused dual-K)
    gemm8<1><<<mb * 4, 512, LDS, stream>>>(
        big2, Wc2b, 4096, 4096, 4096, xc, Wsb, 1024, 1024, 1024,
        (float*)d_out + m * 1024, 1024, 4);
  }
  // LayerNorm in place over the full output
  ln_inplace<<<(int)BT, 256, 0, stream>>>((float*)d_out, gamma, beta);
}